// Round 12
// baseline (368.515 us; speedup 1.0000x reference)
//
#include <hip/hip_runtime.h>
#include <cstdint>
#include <math.h>

#define IN_DIM 256
#define OUT_DIM 27
#define NK1 9
#define PST 28            // param row stride (floats), row-major

// f64 reciprocal via v_rcp_f32 seed + Newton. 2-step ~1 ulp; 1-step ~1.4e-14 rel.
__device__ __forceinline__ double fast_rcp2(double d) {
    double r = (double)__builtin_amdgcn_rcpf((float)d);
    r = r * (2.0 - d * r);
    r = r * (2.0 - d * r);
    return r;
}
__device__ __forceinline__ double fast_rcp1(double d) {
    double r = (double)__builtin_amdgcn_rcpf((float)d);
    r = r * (2.0 - d * r);
    return r;
}

// ---------------------------------------------------------------------------
// GEMV v4: 64 rows/block, 4 waves k-split (wave w: k in [64w,64w+64)).
// W quarter [64][28] per wave in LDS (broadcast b128 reads — R9-proven).
// h staged via wave-private LDS [64 rows][9 float4] per 32-k chunk with
// COALESCED global loads (8 x 1KB wave-contiguous). Pad-9 f4 layout:
// quad-bank = (row+col)%8 -> conflict-free b128 writes AND reads.
// No barriers in the K-loop (same-wave LDS ops are in-order); chunk-1 loads
// sit in registers during FMA-0 (T14 split). One barrier for the reduce.
// ---------------------------------------------------------------------------
__global__ __launch_bounds__(256)
void gemv_params4(const float* __restrict__ h, const float* __restrict__ W,
                  const float* __restrict__ bias, float* __restrict__ params)
{
    __shared__ float wq[4][64 * 28];   // 28.7 KB
    __shared__ float hc[4][64 * 36];   // 36.9 KB ([64 rows][9 f4])
    const int t = threadIdx.x;
    const int w = t >> 6, l = t & 63;
    const size_t row0 = (size_t)blockIdx.x * 64;

    float* wl = wq[w];
    float* hw = hc[w];
    const float* hbase = h + row0 * IN_DIM + w * 64;

    // W quarter gather (tiny, L2) — issued first so later vmcnt waits cover it
    float wtmp[OUT_DIM];
#pragma unroll
    for (int nn = 0; nn < OUT_DIM; ++nn)
        wtmp[nn] = W[nn * IN_DIM + w * 64 + l];

    // chunk-0 h loads: f = i*64+l -> row f/8, col f%8 (fully coalesced)
    float4 st[8];
#pragma unroll
    for (int i = 0; i < 8; ++i) {
        const int f = i * 64 + l;
        st[i] = *reinterpret_cast<const float4*>(
            hbase + (f >> 3) * IN_DIM + (f & 7) * 4);
    }

    // W -> LDS (stride-28 writes, one-time)
#pragma unroll
    for (int nn = 0; nn < OUT_DIM; ++nn) wl[l * 28 + nn] = wtmp[nn];
    wl[l * 28 + 27] = 0.f;

    // chunk0 -> LDS
#pragma unroll
    for (int i = 0; i < 8; ++i) {
        const int f = i * 64 + l;
        *reinterpret_cast<float4*>(hw + ((f >> 3) * 9 + (f & 7)) * 4) = st[i];
    }

    // chunk-1 loads into regs (overlap FMA-0)
#pragma unroll
    for (int i = 0; i < 8; ++i) {
        const int f = i * 64 + l;
        st[i] = *reinterpret_cast<const float4*>(
            hbase + (f >> 3) * IN_DIM + 32 + (f & 7) * 4);
    }

    float acc[28];
#pragma unroll
    for (int i = 0; i < 28; ++i) acc[i] = 0.f;

#define FMA_CHUNK(koff_)                                                      \
    _Pragma("unroll")                                                         \
    for (int c4 = 0; c4 < 8; ++c4) {                                          \
        const float4 hv4 = *reinterpret_cast<const float4*>(                  \
            hw + (l * 9 + c4) * 4);                                           \
        _Pragma("unroll")                                                     \
        for (int kk = 0; kk < 4; ++kk) {                                      \
            const float hv = (kk == 0) ? hv4.x : (kk == 1) ? hv4.y            \
                           : (kk == 2) ? hv4.z : hv4.w;                       \
            const float* wr = wl + ((koff_) + c4 * 4 + kk) * 28;              \
            _Pragma("unroll")                                                 \
            for (int q = 0; q < 7; ++q) {                                     \
                const float4 wv = *reinterpret_cast<const float4*>(wr + q*4); \
                acc[q*4+0] = fmaf(hv, wv.x, acc[q*4+0]);                      \
                acc[q*4+1] = fmaf(hv, wv.y, acc[q*4+1]);                      \
                acc[q*4+2] = fmaf(hv, wv.z, acc[q*4+2]);                      \
                acc[q*4+3] = fmaf(hv, wv.w, acc[q*4+3]);                      \
            }                                                                 \
        }                                                                     \
    }

    FMA_CHUNK(0)

    // chunk1 -> LDS (after chunk0 reads in program order; same-wave LDS in-order)
#pragma unroll
    for (int i = 0; i < 8; ++i) {
        const int f = i * 64 + l;
        *reinterpret_cast<float4*>(hw + ((f >> 3) * 9 + (f & 7)) * 4) = st[i];
    }

    FMA_CHUNK(32)
#undef FMA_CHUNK

    // cross-wave reduce via LDS (reuse hc), then fp32 softplus, row-major store
    __syncthreads();
#pragma unroll
    for (int nn = 0; nn < OUT_DIM; ++nn) hc[w][l * 28 + nn] = acc[nn];
    __syncthreads();

    const int row = t & 63, grp = t >> 6;
#pragma unroll
    for (int j = 0; j < 7; ++j) {
        const int nn = grp * 7 + j;
        if (nn < OUT_DIM) {
            const float s = hc[0][row * 28 + nn] + hc[1][row * 28 + nn]
                          + hc[2][row * 28 + nn] + hc[3][row * 28 + nn];
            const float x  = s + bias[nn];
            const float sp = fmaxf(x, 0.f) + log1pf(expf(-fabsf(x))) + 1e-4f;
            params[(row0 + row) * PST + nn] = sp;
        }
    }
}

// ---------------------------------------------------------------------------
// Spline v4: wave = 1 row (4 rows/block), zero block barriers.
// Params read via readfirstlane'd row -> contiguous s_load burst.
// Setup PARALLEL: lanes 0..8 each build one bin's f64 septet into LDS.
// Bin-select in fp32 (safe: RQS is C1 at knots, boundary misassignment is
// O(eps^2)); eval in f64 (the F-difference cancellation), 1-Newton rcp.
// 2 edges/lane; seam via shfl_down; F(1.0) = 1.0 analytically.
// ---------------------------------------------------------------------------
__global__ __launch_bounds__(256)
void spline_eval4(const float* __restrict__ params, float* __restrict__ out)
{
    __shared__ double cf[4][9][9];   // [wave][bin][{cx,cy,iw,dl,hb,db,sc,-,-}]
    const int t = threadIdx.x;
    const int r = t >> 6, lq = t & 63;
    const int row = __builtin_amdgcn_readfirstlane((int)(blockIdx.x * 4 + r));

    const float* prow = params + (size_t)row * PST;   // uniform -> s_load
    float p[OUT_DIM];
#pragma unroll
    for (int j = 0; j < OUT_DIM; ++j) p[j] = prow[j];

    // fp32 select boundaries cumf[i] = cumx[i+1], all lanes
    float wsf = 0.f;
#pragma unroll
    for (int i = 0; i < 9; ++i) wsf += p[i];
    const float iwf = 1.0f / wsf;
    float cumf[9];
    {
        float s = 0.f;
#pragma unroll
        for (int i = 0; i < 9; ++i) { s += p[i]; cumf[i] = s * iwf; }
    }

    // f64 coeff table: lane b builds bin b
    if (lq < 9) {
        const int b = lq;
        double ws = 0.0, hs = 0.0;
#pragma unroll
        for (int i = 0; i < 9; ++i) { ws += (double)p[i]; hs += (double)p[9 + i]; }
        const double iws = fast_rcp2(ws), ihs = fast_rcp2(hs);
        double pw = 0.0, ph = 0.0;
        for (int i = 0; i < b; ++i) { pw += (double)p[i]; ph += (double)p[9 + i]; }
        const double cx  = pw * iws;
        const double cy  = ph * ihs;
        const double wb  = (double)p[b] * iws;
        const double hb  = (double)p[9 + b] * ihs;
        const double iw  = fast_rcp2(wb);
        const double dl  = hb * iw;
        const double db  = (b == 0) ? 1.0 : (double)p[17 + b];
        const double db1 = (double)p[18 + b];
        cf[r][b][0] = cx;  cf[r][b][1] = cy;  cf[r][b][2] = iw;
        cf[r][b][3] = dl;  cf[r][b][4] = hb;  cf[r][b][5] = db;
        cf[r][b][6] = db + db1 - 2.0 * dl;
    }
    __builtin_amdgcn_wave_barrier();   // same-wave LDS: ordering only

    auto evalF = [&](double x, float xf) -> double {
        int b = 0;
#pragma unroll
        for (int i = 0; i < 9; ++i) b += (cumf[i] < xf) ? 1 : 0;  // searchsorted-left
        b = (b < 8) ? b : 8;
        const double* c = cf[r][b];
        const double th  = (x - c[0]) * c[2];
        const double t1m = th * (1.0 - th);
        const double num = c[4] * (c[3] * th * th + c[5] * t1m);
        const double den = c[3] + c[6] * t1m;
        return c[1] + num * fast_rcp1(den);
    };

    const double x0 = (double)lq * (1.0 / 64.0);
    const double x1 = x0 + (1.0 / 128.0);
    const double F0 = evalF(x0, (float)lq * (1.0f / 64.0f));
    const double F1 = evalF(x1, (float)(2 * lq + 1) * (1.0f / 128.0f));
    const double Fn = __shfl_down(F0, 1);
    const double F2 = (lq == 63) ? 1.0 : Fn;    // F(1.0) = cumy[9] = 1 (+-1e-15)

    const float p0 = __logf(fmaxf((float)(F1 - F0), 1e-8f));
    const float p1 = __logf(fmaxf((float)(F2 - F1), 1e-8f));
    *reinterpret_cast<float2*>(out + (size_t)row * 128 + lq * 2) = make_float2(p0, p1);
}

// ---------------------------------------------------------------------------
// Fallback (ws too small): R5/R8's proven monolithic kernel.
// ---------------------------------------------------------------------------
__device__ __forceinline__ double softplus_d(double x) {
    return fmax(x, 0.0) + log1p(exp(-fabs(x)));
}

__global__ __launch_bounds__(256)
void rqs_head_fallback(const float* __restrict__ h, const float* __restrict__ Wmat,
                       const float* __restrict__ b, float* __restrict__ out) {
    __shared__ float sh[128][33];
    const int t = threadIdx.x, rl = t >> 1, half = t & 1;
    const long row0 = (long)blockIdx.x * 128;
    float acc[OUT_DIM];
#pragma unroll
    for (int i = 0; i < OUT_DIM; ++i) acc[i] = 0.0f;
    for (int kc = 0; kc < 8; ++kc) {
        __syncthreads();
#pragma unroll
        for (int p = 0; p < 4; ++p) {
            const int r = p * 32 + (t / 8), fq = t % 8;
            const float4 v = *reinterpret_cast<const float4*>(
                &h[(row0 + r) * IN_DIM + (size_t)kc * 32 + fq * 4]);
            sh[r][fq*4+0]=v.x; sh[r][fq*4+1]=v.y; sh[r][fq*4+2]=v.z; sh[r][fq*4+3]=v.w;
        }
        __syncthreads();
#pragma unroll
        for (int kk = 0; kk < 16; ++kk) {
            const int kl = half * 16 + kk;
            const float hv = sh[rl][kl];
            const int kg = kc * 32 + kl;
#pragma unroll
            for (int nn = 0; nn < OUT_DIM; ++nn)
                acc[nn] = fmaf(hv, Wmat[nn * IN_DIM + kg], acc[nn]);
        }
    }
#pragma unroll
    for (int nn = 0; nn < OUT_DIM; ++nn) acc[nn] += __shfl_xor(acc[nn], 1);
    double pr[OUT_DIM];
#pragma unroll
    for (int nn = 0; nn < OUT_DIM; ++nn)
        pr[nn] = softplus_d((double)acc[nn] + (double)b[nn]) + 1e-4;
    double wsum = 0.0, hsum = 0.0;
#pragma unroll
    for (int i = 0; i < NK1; ++i) { wsum += pr[i]; hsum += pr[NK1 + i]; }
    const double iws = 1.0 / wsum, ihs = 1.0 / hsum;
    double cumx[NK1+1], cumy[NK1+1], dfull[NK1+1];
    cumx[0]=0.0; cumy[0]=0.0; dfull[0]=1.0;
#pragma unroll
    for (int i = 0; i < NK1; ++i) {
        cumx[i+1] = cumx[i] + pr[i]*iws;
        cumy[i+1] = cumy[i] + pr[NK1+i]*ihs;
        dfull[i+1] = pr[2*NK1+i];
    }
    const int e0 = half * 64, eend = e0 + 64;
    int e = e0; double prevF = 0.0;
    float* orow = out + (row0 + rl) * 128;
#define BIN_BODY(bin_) { \
    const double cx=cumx[bin_], cxn=((bin_)<8)?cumx[(bin_)+1]:1.0e300, cy=cumy[bin_]; \
    const double wb=cumx[(bin_)+1]-cx, hb=cumy[(bin_)+1]-cy; \
    const double iw=1.0/wb, dl=hb*iw, db=dfull[bin_], db1=dfull[(bin_)+1]; \
    const double sc=db+db1-2.0*dl; \
    while (e <= eend) { \
        const double x=(double)e*0.0078125; \
        if (x > cxn) break; \
        const double th=(x-cx)*iw, t1m=th*(1.0-th); \
        const double num=hb*(dl*th*th+db*t1m), den=dl+sc*t1m; \
        const double F=cy+num/den; \
        if (e > e0) orow[e-1] = logf(fmaxf((float)(F-prevF), 1e-8f)); \
        prevF=F; ++e; \
    } }
    BIN_BODY(0) BIN_BODY(1) BIN_BODY(2) BIN_BODY(3) BIN_BODY(4)
    BIN_BODY(5) BIN_BODY(6) BIN_BODY(7) BIN_BODY(8)
#undef BIN_BODY
}

// ---------------------------------------------------------------------------
extern "C" void kernel_launch(void* const* d_in, const int* in_sizes, int n_in,
                              void* d_out, int out_size, void* d_ws, size_t ws_size,
                              hipStream_t stream) {
    const float* h = (const float*)d_in[0];
    const float* W = (const float*)d_in[1];
    const float* b = (const float*)d_in[2];
    float* out = (float*)d_out;

    const int rows = in_sizes[0] / IN_DIM;   // 131072
    const size_t need = (size_t)rows * PST * sizeof(float);   // 14.7 MB

    if (ws_size >= need) {
        float* params = (float*)d_ws;
        gemv_params4 <<<rows / 64, 256, 0, stream>>>(h, W, b, params);
        spline_eval4 <<<rows / 4,  256, 0, stream>>>(params, out);
    } else {
        rqs_head_fallback<<<rows / 128, 256, 0, stream>>>(h, W, b, out);
    }
}